// Round 4
// baseline (308.871 us; speedup 1.0000x reference)
//
#include <hip/hip_runtime.h>

static constexpr int N  = 100000;
static constexpr int E  = 1600000;
static constexpr int B  = 256;

static constexpr int NBLK   = 250;            // partition blocks
static constexpr int CHUNK  = E / NBLK;       // 6400 edges per block
static constexpr int PERT   = CHUNK / B;      // 25 edges per thread
static constexpr int NBUCK  = 782;            // ceil(N/128) buckets of 128 nodes
static constexpr int NCNT   = NBUCK * NBLK;   // 195500 count-matrix entries
static constexpr int NSB    = (NCNT + B - 1) / B;  // 764 scan blocks

// global base of (bucket,block) slice = scanned[] + bsum[] (add-back folded in)
__device__ __forceinline__ int gbase(const int* scanned, const int* bsum, int idx) {
    return scanned[idx] + bsum[idx >> 8];
}

// ---- phase A: per-block bucket histogram ------------------------------------

__global__ void kA_hist(const int* __restrict__ dst, int* __restrict__ counts) {
    __shared__ int hist[NBUCK];
    int t = threadIdx.x, blk = blockIdx.x;
    for (int i = t; i < NBUCK; i += B) hist[i] = 0;
    __syncthreads();
    int eb = blk * CHUNK;
#pragma unroll
    for (int k = 0; k < PERT; ++k) {
        int d = dst[eb + k * B + t];
        atomicAdd(&hist[d >> 7], 1);
    }
    __syncthreads();
    for (int b = t; b < NBUCK; b += B) counts[b * NBLK + blk] = hist[b];
}

// ---- scan: block-exclusive + block sums -------------------------------------

__global__ void ks1(const int* __restrict__ counts, int* __restrict__ scanned,
                    int* __restrict__ bsum) {
    __shared__ int s[B];
    int t = threadIdx.x;
    int g = blockIdx.x * B + t;
    s[t] = (g < NCNT) ? counts[g] : 0;
    __syncthreads();
    for (int off = 1; off < B; off <<= 1) {
        int v = (t >= off) ? s[t - off] : 0;
        __syncthreads();
        s[t] += v;
        __syncthreads();
    }
    if (g < NCNT) scanned[g] = (t == 0) ? 0 : s[t - 1];
    if (t == B - 1) bsum[blockIdx.x] = s[t];
}

__global__ void ks2(int* __restrict__ bsum) {
    __shared__ int s[1024];
    int t = threadIdx.x;
    s[t] = (t < NSB) ? bsum[t] : 0;
    __syncthreads();
    for (int off = 1; off < 1024; off <<= 1) {
        int v = (t >= off) ? s[t - off] : 0;
        __syncthreads();
        s[t] += v;
        __syncthreads();
    }
    if (t < NSB) bsum[t] = (t == 0) ? 0 : s[t - 1];
}

// ---- phase C: stable partition with LDS staging -----------------------------

__global__ void kC_scatter(const int* __restrict__ src, const int* __restrict__ dst,
                           const int* __restrict__ scanned, const int* __restrict__ bsum,
                           int* __restrict__ packed) {
    __shared__ int lbase[NBUCK];   // local hist -> exclusive local base
    __shared__ int cnt2[NBUCK];
    __shared__ int gb[NBUCK];
    __shared__ int partial[B];
    __shared__ int stage[CHUNK];

    int t = threadIdx.x, blk = blockIdx.x;
    for (int i = t; i < NBUCK; i += B) { lbase[i] = 0; cnt2[i] = 0; }
    __syncthreads();

    int eb = blk * CHUNK;
    int ds[PERT], ss[PERT];
#pragma unroll
    for (int k = 0; k < PERT; ++k) {
        int e = eb + k * B + t;
        ds[k] = dst[e];
        ss[k] = src[e];
        atomicAdd(&lbase[ds[k] >> 7], 1);
    }
    __syncthreads();

    // exclusive scan of lbase[0..NBUCK): 4 elems/thread blocked + HS over partials
    int v0, v1, v2, v3;
    {
        int i0 = 4 * t;
        v0 = (i0 + 0 < NBUCK) ? lbase[i0 + 0] : 0;
        v1 = (i0 + 1 < NBUCK) ? lbase[i0 + 1] : 0;
        v2 = (i0 + 2 < NBUCK) ? lbase[i0 + 2] : 0;
        v3 = (i0 + 3 < NBUCK) ? lbase[i0 + 3] : 0;
        partial[t] = v0 + v1 + v2 + v3;
    }
    __syncthreads();
    for (int off = 1; off < B; off <<= 1) {
        int v = (t >= off) ? partial[t - off] : 0;
        __syncthreads();
        partial[t] += v;
        __syncthreads();
    }
    {
        int run = (t == 0) ? 0 : partial[t - 1];
        int i0 = 4 * t;
        if (i0 + 0 < NBUCK) lbase[i0 + 0] = run; run += v0;
        if (i0 + 1 < NBUCK) lbase[i0 + 1] = run; run += v1;
        if (i0 + 2 < NBUCK) lbase[i0 + 2] = run; run += v2;
        if (i0 + 3 < NBUCK) lbase[i0 + 3] = run;
    }
    // preload this block's global bases
    for (int b = t; b < NBUCK; b += B)
        gb[b] = gbase(scanned, bsum, b * NBLK + blk);
    __syncthreads();

    // place into LDS stage, packed as (dst&127)<<17 | src
#pragma unroll
    for (int k = 0; k < PERT; ++k) {
        int d = ds[k], b = d >> 7;
        int r = atomicAdd(&cnt2[b], 1);
        stage[lbase[b] + r] = ss[k] | ((d & 127) << 17);
    }
    __syncthreads();

    // write out: thread t owns slots [t*PERT, (t+1)*PERT); runs are coalesced
    int slot0 = t * PERT;
    int b = 0;
    for (int step = 512; step; step >>= 1) {
        int nb = b + step;
        if (nb < NBUCK && lbase[nb] <= slot0) b = nb;
    }
#pragma unroll
    for (int j = 0; j < PERT; ++j) {
        int slot = slot0 + j;
        while (b + 1 < NBUCK && lbase[b + 1] <= slot) ++b;
        packed[gb[b] + (slot - lbase[b])] = stage[slot];
    }
}

// ---- phase D1: per-bucket degree -> dis -------------------------------------

__global__ void kD1_deg(const int* __restrict__ packed, const int* __restrict__ scanned,
                        const int* __restrict__ bsum, float* __restrict__ dis) {
    __shared__ int c[128];
    int t = threadIdx.x, b = blockIdx.x;
    if (t < 128) c[t] = 0;
    __syncthreads();
    int e0 = gbase(scanned, bsum, b * NBLK);
    int e1 = (b == NBUCK - 1) ? E : gbase(scanned, bsum, (b + 1) * NBLK);
    for (int e = e0 + t; e < e1; e += B)
        atomicAdd(&c[packed[e] >> 17], 1);
    __syncthreads();
    int nbase = b * 128;
    int ncnt = min(128, N - nbase);
    if (t < ncnt) dis[nbase + t] = rsqrtf((float)(c[t] + 1));
}

// ---- phase D2: layer-1 aggregation (LDS acc) + fused dense ------------------

__global__ void kD2_agg(const float* __restrict__ x, const float* __restrict__ dis,
                        const int* __restrict__ packed, const int* __restrict__ scanned,
                        const int* __restrict__ bsum,
                        const float* __restrict__ W1, const float* __restrict__ b1,
                        const float* __restrict__ W2, float* __restrict__ h2p) {
    __shared__ float acc[128 * 17];   // padded row: bank spread
    __shared__ float sW1[512], sb1[32], sW2[64], sdis[128];
    int t = threadIdx.x, b = blockIdx.x;
    for (int i = t; i < 512; i += B) sW1[i] = W1[i];
    if (t < 32) sb1[t] = b1[t];
    if (t < 64) sW2[t] = W2[t];

    int nbase = b * 128;
    int ncnt = min(128, N - nbase);
    const float4* x4 = (const float4*)x;
    if (t < 128) {
        float d = (t < ncnt) ? dis[nbase + t] : 0.f;
        sdis[t] = d;
        float d2 = d * d;
        float* row = acc + t * 17;
        if (t < ncnt) {
#pragma unroll
            for (int j = 0; j < 4; ++j) {
                float4 v = x4[(size_t)(nbase + t) * 4 + j];
                row[j * 4 + 0] = v.x * d2; row[j * 4 + 1] = v.y * d2;
                row[j * 4 + 2] = v.z * d2; row[j * 4 + 3] = v.w * d2;
            }
        }
    }
    __syncthreads();

    int e0 = gbase(scanned, bsum, b * NBLK);
    int e1 = (b == NBUCK - 1) ? E : gbase(scanned, bsum, (b + 1) * NBLK);
    for (int e = e0 + t; e < e1; e += B) {
        int p = packed[e];
        int s = p & 0x1FFFF;
        int lo = p >> 17;
        float nrm = dis[s] * sdis[lo];
        const float4* xp = x4 + (size_t)s * 4;
        float4 v0 = xp[0], v1 = xp[1], v2 = xp[2], v3 = xp[3];
        float* row = acc + lo * 17;
        atomicAdd(&row[0],  v0.x * nrm); atomicAdd(&row[1],  v0.y * nrm);
        atomicAdd(&row[2],  v0.z * nrm); atomicAdd(&row[3],  v0.w * nrm);
        atomicAdd(&row[4],  v1.x * nrm); atomicAdd(&row[5],  v1.y * nrm);
        atomicAdd(&row[6],  v1.z * nrm); atomicAdd(&row[7],  v1.w * nrm);
        atomicAdd(&row[8],  v2.x * nrm); atomicAdd(&row[9],  v2.y * nrm);
        atomicAdd(&row[10], v2.z * nrm); atomicAdd(&row[11], v2.w * nrm);
        atomicAdd(&row[12], v3.x * nrm); atomicAdd(&row[13], v3.y * nrm);
        atomicAdd(&row[14], v3.z * nrm); atomicAdd(&row[15], v3.w * nrm);
    }
    __syncthreads();

    // fused dense: h2p = relu(acc @ W1 + b1) @ W2
    if (t < ncnt) {
        const float* row = acc + t * 17;
        float xi[16];
#pragma unroll
        for (int k = 0; k < 16; ++k) xi[k] = row[k];
        float o0 = 0.f, o1 = 0.f;
#pragma unroll
        for (int c = 0; c < 32; ++c) {
            float h = sb1[c];
#pragma unroll
            for (int k = 0; k < 16; ++k) h = fmaf(xi[k], sW1[k * 32 + c], h);
            h = fmaxf(h, 0.f);
            o0 = fmaf(h, sW2[c * 2 + 0], o0);
            o1 = fmaf(h, sW2[c * 2 + 1], o1);
        }
        ((float2*)h2p)[nbase + t] = make_float2(o0, o1);
    }
}

// ---- phase F: layer-2 aggregation + bias ------------------------------------

__global__ void kF_l2(const float* __restrict__ h2p, const float* __restrict__ dis,
                      const int* __restrict__ packed, const int* __restrict__ scanned,
                      const int* __restrict__ bsum, const float* __restrict__ b2,
                      float* __restrict__ out) {
    __shared__ float a2[128 * 2];
    __shared__ float sdis[128];
    int t = threadIdx.x, b = blockIdx.x;
    int nbase = b * 128;
    int ncnt = min(128, N - nbase);
    const float2* h2 = (const float2*)h2p;
    if (t < 128) {
        float d = (t < ncnt) ? dis[nbase + t] : 0.f;
        sdis[t] = d;
        if (t < ncnt) {
            float d2 = d * d;
            float2 hv = h2[nbase + t];
            a2[t * 2 + 0] = fmaf(hv.x, d2, b2[0]);
            a2[t * 2 + 1] = fmaf(hv.y, d2, b2[1]);
        }
    }
    __syncthreads();
    int e0 = gbase(scanned, bsum, b * NBLK);
    int e1 = (b == NBUCK - 1) ? E : gbase(scanned, bsum, (b + 1) * NBLK);
    for (int e = e0 + t; e < e1; e += B) {
        int p = packed[e];
        int s = p & 0x1FFFF;
        int lo = p >> 17;
        float nrm = dis[s] * sdis[lo];
        float2 v = h2[s];
        atomicAdd(&a2[lo * 2 + 0], v.x * nrm);
        atomicAdd(&a2[lo * 2 + 1], v.y * nrm);
    }
    __syncthreads();
    if (t < ncnt)
        ((float2*)out)[nbase + t] = make_float2(a2[t * 2], a2[t * 2 + 1]);
}

// ---- launcher ---------------------------------------------------------------

extern "C" void kernel_launch(void* const* d_in, const int* in_sizes, int n_in,
                              void* d_out, int out_size, void* d_ws, size_t ws_size,
                              hipStream_t stream) {
    const float* x  = (const float*)d_in[0];
    const int*   ei = (const int*)d_in[1];
    const float* W1 = (const float*)d_in[2];
    const float* b1 = (const float*)d_in[3];
    const float* W2 = (const float*)d_in[4];
    const float* b2 = (const float*)d_in[5];
    float* out = (float*)d_out;

    const int* src = ei;
    const int* dst = ei + E;

    // workspace layout (4-byte words; all even offsets so float2 views align)
    int*   packed  = (int*)d_ws;                       // E
    int*   counts  = packed + E;                       // NSB*B (>= NCNT)
    int*   scanned = counts + NSB * B;                 // NSB*B
    int*   bsum    = scanned + NSB * B;                // 1024
    float* dis     = (float*)(bsum + 1024);            // N
    float* h2p     = dis + N;                          // 2N

    kA_hist<<<NBLK, B, 0, stream>>>(dst, counts);
    ks1<<<NSB, B, 0, stream>>>(counts, scanned, bsum);
    ks2<<<1, 1024, 0, stream>>>(bsum);
    kC_scatter<<<NBLK, B, 0, stream>>>(src, dst, scanned, bsum, packed);
    kD1_deg<<<NBUCK, B, 0, stream>>>(packed, scanned, bsum, dis);
    kD2_agg<<<NBUCK, B, 0, stream>>>(x, dis, packed, scanned, bsum, W1, b1, W2, h2p);
    kF_l2<<<NBUCK, B, 0, stream>>>(h2p, dis, packed, scanned, bsum, b2, out);
}